// Round 5
// baseline (135.812 us; speedup 1.0000x reference)
//
#include <hip/hip_runtime.h>
#include <hip/hip_bf16.h>
#include <hip/hip_fp16.h>

#define B_SZ 1024
#define T_LEN 8192
#define NBINS 819            // T//10
#define PSD_LDA 1664         // padded bf16 row stride (zero-padded 1638..1663)
#define PI_F 3.14159265358979323846f

typedef __attribute__((ext_vector_type(8))) short bf16x8;
typedef __attribute__((ext_vector_type(4))) float f32x4;

// ---- compile-time FFT tables ----------------------------------------------
__device__ constexpr float C32T[16] = {
  1.0f, 0.980785280f, 0.923879533f, 0.831469612f, 0.707106781f, 0.555570233f,
  0.382683432f, 0.195090322f, 0.0f, -0.195090322f, -0.382683432f, -0.555570233f,
  -0.707106781f, -0.831469612f, -0.923879533f, -0.980785280f};
__device__ constexpr float S32T[16] = {   // -sin(2*pi*k/32)
  0.0f, -0.195090322f, -0.382683432f, -0.555570233f, -0.707106781f,
  -0.831469612f, -0.923879533f, -0.980785280f, -1.0f, -0.980785280f,
  -0.923879533f, -0.831469612f, -0.707106781f, -0.555570233f, -0.382683432f,
  -0.195090322f};
__device__ constexpr int BR5[32] = {   // 5-bit bit-reverse
  0,16,8,24,4,20,12,28,2,18,10,26,6,22,14,30,
  1,17,9,25,5,21,13,29,3,19,11,27,7,23,15,31};
__device__ constexpr float E8C[8] = {  // cos(pi*c/4)  (W_8^{7c} = e^{+i pi c/4})
  1.0f, 0.707106781f, 0.0f, -0.707106781f, -1.0f, -0.707106781f, 0.0f, 0.707106781f};
__device__ constexpr float E8S[8] = {  // sin(pi*c/4)
  0.0f, 0.707106781f, 1.0f, 0.707106781f, 0.0f, -0.707106781f, -1.0f, -0.707106781f};

template<int S>
__device__ __forceinline__ void fft32_stage(float (&xr)[32], float (&xi)[32]) {
  #pragma unroll
  for (int o = 0; o < 32; o += 2 * S) {
    #pragma unroll
    for (int j = 0; j < S; ++j) {
      const int i0 = o + j, i1 = o + j + S;
      float ur = xr[i0] + xr[i1], ui = xi[i0] + xi[i1];
      float dr = xr[i0] - xr[i1], di = xi[i0] - xi[i1];
      const float c = C32T[j * (16 / S)], sn = S32T[j * (16 / S)];
      xr[i0] = ur; xi[i0] = ui;
      xr[i1] = dr * c - di * sn;
      xi[i1] = dr * sn + di * c;
    }
  }
}
__device__ __forceinline__ void fft32(float (&xr)[32], float (&xi)[32]) {
  fft32_stage<16>(xr, xi); fft32_stage<8>(xr, xi); fft32_stage<4>(xr, xi);
  fft32_stage<2>(xr, xi);  fft32_stage<1>(xr, xi);
  // X[k] sits at register index BR5[k]
}

// ---------------------------------------------------------------------------
// Kernel 1: normalize feature rows (B x 256) -> bf16
// ---------------------------------------------------------------------------
__global__ __launch_bounds__(256) void normalize_kernel(
    const float* __restrict__ f, __hip_bfloat16* __restrict__ fn) {
  int i = blockIdx.x;
  int t = threadIdx.x;
  float v = f[(size_t)i * 256 + t];
  float s = v * v;
  #pragma unroll
  for (int o = 32; o; o >>= 1) s += __shfl_down(s, o);
  __shared__ float buf[4];
  if ((t & 63) == 0) buf[t >> 6] = s;
  __syncthreads();
  float norm = sqrtf(buf[0] + buf[1] + buf[2] + buf[3]);
  norm = fmaxf(norm, 1e-12f);
  fn[(size_t)i * 256 + t] = __float2bfloat16(v / norm);
}

// ---------------------------------------------------------------------------
// Kernel 2: per-trajectory stats, 8192 = 32 x 32 x 8, fp16 LDS intermediates.
// 256 threads, 32 complex/thread; LDS 32 KB -> 4 blocks/CU (16 waves/CU).
// n = 256a + 8b + c (tid = 8b+c); k = k0 + 32k1 + 1024k2.
//   S1: FFT32 over a -> *W_8192^{tid*k0} -> T1 (half2, swizzled)
//   S2: FFT32 over b -> *W_256^{cr*k1}   -> T2 (half2, swizzled)
//   S3: partial DFT8 over c, k2 in {0,7} -> fp32 in reused LDS
// ---------------------------------------------------------------------------
__global__ __launch_bounds__(256, 4) void traj_stats_kernel(
    const float4* __restrict__ traj,
    __hip_bfloat16* __restrict__ psd,
    float2* __restrict__ vmean,
    float2* __restrict__ wind) {
  __shared__ __half2 z2[T_LEN];   // 32 KB
  __shared__ float rsum[2][4];
  __shared__ float phb[4];

  const int tid = threadIdx.x;
  const float4* row = traj + (size_t)blockIdx.x * T_LEN;
  const int b = tid >> 3, c = tid & 7;   // also (k0r, cr) for the read side

  if (tid == 0) {   // phase endpoints: two tiny direct loads, no reg pressure
    float4 r0 = row[0];
    float4 r1 = row[T_LEN - 1];
    phb[0] = r0.x; phb[1] = r0.z; phb[2] = r1.x; phb[3] = r1.z;
  }

  float xr[32], xi[32];
  float sum0 = 0.f, sum1 = 0.f;
  const float wstep = 2.0f * PI_F / (float)T_LEN;

  #pragma unroll
  for (int g = 0; g < 4; ++g) {
    float4 rb[8];
    #pragma unroll
    for (int i = 0; i < 8; ++i) rb[i] = row[(g * 8 + i) * 256 + tid];
    #pragma unroll
    for (int i = 0; i < 8; ++i) {
      const int a = g * 8 + i;
      sum0 += rb[i].y; sum1 += rb[i].w;
      float w = 0.5f * (1.0f - __cosf(wstep * (float)(a * 256 + tid)));
      xr[a] = rb[i].y * w;
      xi[a] = rb[i].w * w;
    }
  }

  // ---- stage 1: FFT32 over a
  fft32(xr, xi);

  // twiddle W_8192^{tid*k0} fused with T1 write
  // T1 word(k0,b,c) = k0*256 + ((b + (k0&3))&31)*8 + c   (<=2-way both sides)
  {
    float s1, c1, s16, c16;
    __sincosf(-2.0f * PI_F * (float)tid / 8192.0f, &s1, &c1);
    __sincosf(-2.0f * PI_F * (float)tid / 512.0f,  &s16, &c16);
    float wr0 = 1.f, wi0 = 0.f, wr1 = c16, wi1 = s16;
    #pragma unroll
    for (int k0 = 0; k0 < 16; ++k0) {
      {
        const int r = BR5[k0];
        float tr = xr[r] * wr0 - xi[r] * wi0;
        float ti = xr[r] * wi0 + xi[r] * wr0;
        z2[k0 * 256 + (((b + (k0 & 3)) & 31) << 3) + c] = __floats2half2_rn(tr, ti);
        float nr = wr0 * c1 - wi0 * s1; wi0 = wr0 * s1 + wi0 * c1; wr0 = nr;
      }
      {
        const int k0b = k0 + 16;
        const int r = BR5[k0b];
        float tr = xr[r] * wr1 - xi[r] * wi1;
        float ti = xr[r] * wi1 + xi[r] * wr1;
        z2[k0b * 256 + (((b + (k0b & 3)) & 31) << 3) + c] = __floats2half2_rn(tr, ti);
        float nr = wr1 * c1 - wi1 * s1; wi1 = wr1 * s1 + wi1 * c1; wr1 = nr;
      }
    }
  }
  __syncthreads();

  // ---- T1 read: thread (k0r=b, cr=c) gathers over b' (static reg indices)
  #pragma unroll
  for (int bq = 0; bq < 32; ++bq) {
    __half2 v = z2[b * 256 + (((bq + (b & 3)) & 31) << 3) + c];
    xr[bq] = __low2float(v); xi[bq] = __high2float(v);
  }
  __syncthreads();   // all reads done before in-place overwrite

  // ---- stage 2: FFT32 over b
  fft32(xr, xi);

  // twiddle W_256^{cr*k1} fused with T2 write
  // T2 word(p,c) = p*8 + (c ^ ((p>>2)&7)), p = k1*32 + k0r  (<=2-way both sides)
  {
    float s1, c1, s16, c16;
    __sincosf(-2.0f * PI_F * (float)c / 256.0f, &s1, &c1);
    __sincosf(-2.0f * PI_F * (float)c / 16.0f,  &s16, &c16);
    float wr0 = 1.f, wi0 = 0.f, wr1 = c16, wi1 = s16;
    #pragma unroll
    for (int k1 = 0; k1 < 16; ++k1) {
      {
        const int r = BR5[k1];
        const int p = (k1 << 5) + b;
        float tr = xr[r] * wr0 - xi[r] * wi0;
        float ti = xr[r] * wi0 + xi[r] * wr0;
        z2[(p << 3) + (c ^ ((p >> 2) & 7))] = __floats2half2_rn(tr, ti);
        float nr = wr0 * c1 - wi0 * s1; wi0 = wr0 * s1 + wi0 * c1; wr0 = nr;
      }
      {
        const int k1b = k1 + 16;
        const int r = BR5[k1b];
        const int p = (k1b << 5) + b;
        float tr = xr[r] * wr1 - xi[r] * wi1;
        float ti = xr[r] * wi1 + xi[r] * wr1;
        z2[(p << 3) + (c ^ ((p >> 2) & 7))] = __floats2half2_rn(tr, ti);
        float nr = wr1 * c1 - wi1 * s1; wi1 = wr1 * s1 + wi1 * c1; wr1 = nr;
      }
    }
  }
  __syncthreads();

  // ---- stage 3: partial DFT8 over c; 4 p-values per thread, k2 in {0,7}
  float z0r[4], z0i[4], z7r[4], z7i[4];
  #pragma unroll
  for (int q = 0; q < 4; ++q) {
    const int p = q * 256 + tid;
    float s0r = 0.f, s0i = 0.f, s7r = 0.f, s7i = 0.f;
    #pragma unroll
    for (int c2 = 0; c2 < 8; ++c2) {
      __half2 v = z2[(p << 3) + (c2 ^ ((p >> 2) & 7))];
      float vr = __low2float(v), vi = __high2float(v);
      s0r += vr; s0i += vi;
      s7r += vr * E8C[c2] - vi * E8S[c2];
      s7i += vr * E8S[c2] + vi * E8C[c2];
    }
    z0r[q] = s0r; z0i[q] = s0i; z7r[q] = s7r; z7i[q] = s7i;
  }
  __syncthreads();   // all stage-3 reads done
  float2* zf = (float2*)z2;   // fp32 result region: 2048 float2 = 16 KB
  #pragma unroll
  for (int q = 0; q < 4; ++q) {
    const int p = q * 256 + tid;
    zf[p]        = make_float2(z0r[q], z0i[q]);   // Z[p], p in [0,1024)
    zf[1024 + p] = make_float2(z7r[q], z7i[q]);   // Z[7168+p]
  }
  __syncthreads();

  // ---- unpack packed real FFTs -> psd (bf16), zero-pad to PSD_LDA
  for (int k = tid; k < PSD_LDA / 2; k += 256) {
    if (k < NBINS) {
      float2 Zk = zf[k];
      float2 Zn = (k == 0) ? zf[0] : zf[2048 - k];   // Z[8192-k]
      float fxr = 0.5f * (Zk.x + Zn.x);
      float fxi = 0.5f * (Zk.y - Zn.y);
      float fyr = 0.5f * (Zk.y + Zn.y);
      float fyi = 0.5f * (Zn.x - Zk.x);
      psd[(size_t)blockIdx.x * PSD_LDA + 2*k]     = __float2bfloat16(fxr*fxr + fxi*fxi);
      psd[(size_t)blockIdx.x * PSD_LDA + 2*k + 1] = __float2bfloat16(fyr*fyr + fyi*fyi);
    } else {
      psd[(size_t)blockIdx.x * PSD_LDA + 2*k]     = __float2bfloat16(0.0f);
      psd[(size_t)blockIdx.x * PSD_LDA + 2*k + 1] = __float2bfloat16(0.0f);
    }
  }

  // ---- v_mean and winding
  #pragma unroll
  for (int o = 32; o; o >>= 1) {
    sum0 += __shfl_down(sum0, o);
    sum1 += __shfl_down(sum1, o);
  }
  if ((tid & 63) == 0) { rsum[0][tid >> 6] = sum0; rsum[1][tid >> 6] = sum1; }
  __syncthreads();
  if (tid == 0) {
    float s0 = rsum[0][0] + rsum[0][1] + rsum[0][2] + rsum[0][3];
    float s1v = rsum[1][0] + rsum[1][1] + rsum[1][2] + rsum[1][3];
    vmean[blockIdx.x] = make_float2(s0 / (float)T_LEN, s1v / (float)T_LEN);
    const float inv2pi = 0.15915494309189535f;
    wind[blockIdx.x] = make_float2(fabsf(rintf((phb[2] - phb[0]) * inv2pi)),
                                   fabsf(rintf((phb[3] - phb[1]) * inv2pi)));
  }
}

// ---------------------------------------------------------------------------
// Kernel 3: C = A * A^T, A (1024 x K bf16, stride LDA), MFMA 16x16x32 bf16.
// ---------------------------------------------------------------------------
template<int K, int LDA>
__global__ __launch_bounds__(256) void gram_mfma_kernel(
    const __hip_bfloat16* __restrict__ A, float* __restrict__ C) {
  __shared__ __align__(16) __hip_bfloat16 lds[2][64][64];  // 16 KB
  const int tid  = threadIdx.x;
  const int lane = tid & 63;
  const int wave = tid >> 6;
  const int wm = wave >> 1, wn = wave & 1;
  const int i0 = blockIdx.y * 64;
  const int j0 = blockIdx.x * 64;

  f32x4 acc[2][2] = {};

  for (int k0 = 0; k0 < K; k0 += 64) {
    #pragma unroll
    for (int r = 0; r < 2; ++r) {
      int e   = tid + 256 * r;
      int row = e >> 3;
      int cb  = e & 7;
      int scb = cb ^ (row & 7);
      const __hip_bfloat16* srcA = A + (size_t)(i0 + row) * LDA + k0 + scb * 8;
      const __hip_bfloat16* srcB = A + (size_t)(j0 + row) * LDA + k0 + scb * 8;
      __builtin_amdgcn_global_load_lds(
          (const __attribute__((address_space(1))) void*)srcA,
          (__attribute__((address_space(3))) void*)(&lds[0][0][0] + e * 8),
          16, 0, 0);
      __builtin_amdgcn_global_load_lds(
          (const __attribute__((address_space(1))) void*)srcB,
          (__attribute__((address_space(3))) void*)(&lds[1][0][0] + e * 8),
          16, 0, 0);
    }
    __syncthreads();

    #pragma unroll
    for (int ks = 0; ks < 2; ++ks) {
      bf16x8 afr[2], bfr[2];
      #pragma unroll
      for (int m = 0; m < 2; ++m) {
        int row = wm * 32 + m * 16 + (lane & 15);
        int cidx = ks * 4 + (lane >> 4);
        int cc  = cidx ^ (row & 7);
        afr[m] = *(const bf16x8*)(&lds[0][row][cc * 8]);
      }
      #pragma unroll
      for (int n = 0; n < 2; ++n) {
        int row = wn * 32 + n * 16 + (lane & 15);
        int cidx = ks * 4 + (lane >> 4);
        int cc  = cidx ^ (row & 7);
        bfr[n] = *(const bf16x8*)(&lds[1][row][cc * 8]);
      }
      #pragma unroll
      for (int m = 0; m < 2; ++m)
        #pragma unroll
        for (int n = 0; n < 2; ++n)
          acc[m][n] = __builtin_amdgcn_mfma_f32_16x16x32_bf16(
              afr[m], bfr[n], acc[m][n], 0, 0, 0);
    }
    __syncthreads();
  }

  #pragma unroll
  for (int m = 0; m < 2; ++m)
    #pragma unroll
    for (int n = 0; n < 2; ++n)
      #pragma unroll
      for (int r = 0; r < 4; ++r) {
        int row = i0 + wm * 32 + m * 16 + (lane >> 4) * 4 + r;
        int col = j0 + wn * 32 + n * 16 + (lane & 15);
        C[(size_t)row * B_SZ + col] = acc[m][n][r];
      }
}

// ---------------------------------------------------------------------------
// Kernel 4: per-row loss. One block per row i.
// ---------------------------------------------------------------------------
__global__ __launch_bounds__(256) void loss_rows_kernel(
    const float* __restrict__ S,
    const float* __restrict__ G,
    const float* __restrict__ labels,
    const float* __restrict__ scales,
    const float2* __restrict__ vmean,
    const float2* __restrict__ wind,
    float* __restrict__ row_loss) {
  const int i = blockIdx.x;
  const int tid = threadIdx.x;
  const float inv_scale = 1.0f / scales[0];
  const float l0 = labels[i*3+0], l1 = labels[i*3+1], l2 = labels[i*3+2];
  const float2 vmi = vmean[i];
  const float2 wi  = wind[i];
  const float n2i  = G[(size_t)i * B_SZ + i];
  const float normi = sqrtf(n2i);

  float posw = 0.f, den = 0.f;
  for (int j = tid; j < B_SZ; j += 256) {
    if (j == i) continue;
    float e = __expf(S[(size_t)i * B_SZ + j] * 10.0f);
    den += e;

    float d0 = (labels[j*3+0] - l0) * inv_scale;
    float d1 = (labels[j*3+1] - l1) * inv_scale;
    float d2v = (labels[j*3+2] - l2) * inv_scale;
    float pd = sqrtf(d0*d0 + d1*d1 + d2v*d2v);
    float pw = __expf(-pd * 10.0f);

    float2 vmj = vmean[j];
    float dvx = vmi.x - vmj.x, dvy = vmi.y - vmj.y;
    float v_sim = __expf(-sqrtf(dvx*dvx + dvy*dvy) * 2.0f);

    float n2j = G[(size_t)j * B_SZ + j];
    float g   = G[(size_t)i * B_SZ + j];
    float dd  = fmaxf(n2i + n2j - 2.0f * g, 0.0f);
    float psd_dist = sqrtf(dd);
    float norma = (i < j) ? normi : sqrtf(n2j);
    float psd_sim = __expf(-psd_dist / (norma + 1e-8f));

    float2 wj = wind[j];
    float w_sim = (wi.x == wj.x && wi.y == wj.y) ? 1.0f : 0.0f;

    float kin = 0.4f * v_sim + 0.4f * psd_sim + 0.2f * w_sim;
    posw += e * pw * kin;
  }

  #pragma unroll
  for (int o = 32; o; o >>= 1) {
    posw += __shfl_down(posw, o);
    den  += __shfl_down(den, o);
  }
  __shared__ float bp[4], bd[4];
  if ((tid & 63) == 0) { bp[tid >> 6] = posw; bd[tid >> 6] = den; }
  __syncthreads();
  if (tid == 0) {
    float P = bp[0] + bp[1] + bp[2] + bp[3];
    float D = bd[0] + bd[1] + bd[2] + bd[3];
    row_loss[i] = -logf((P + 1e-8f) / (D + 1e-8f));
  }
}

// ---------------------------------------------------------------------------
// Kernel 5: mean of row losses -> scalar
// ---------------------------------------------------------------------------
__global__ __launch_bounds__(256) void reduce_mean_kernel(
    const float* __restrict__ row_loss, float* __restrict__ out) {
  int tid = threadIdx.x;
  float s = 0.f;
  for (int i = tid; i < B_SZ; i += 256) s += row_loss[i];
  #pragma unroll
  for (int o = 32; o; o >>= 1) s += __shfl_down(s, o);
  __shared__ float buf[4];
  if ((tid & 63) == 0) buf[tid >> 6] = s;
  __syncthreads();
  if (tid == 0) out[0] = (buf[0] + buf[1] + buf[2] + buf[3]) / (float)B_SZ;
}

// ---------------------------------------------------------------------------
extern "C" void kernel_launch(void* const* d_in, const int* in_sizes, int n_in,
                              void* d_out, int out_size, void* d_ws, size_t ws_size,
                              hipStream_t stream) {
  const float* features = (const float*)d_in[0];
  const float* labels   = (const float*)d_in[1];
  const float* traj     = (const float*)d_in[2];
  const float* scales   = (const float*)d_in[3];

  char* ws = (char*)d_ws;
  __hip_bfloat16* f_n = (__hip_bfloat16*)ws;
  __hip_bfloat16* psd = (__hip_bfloat16*)(ws + (size_t)B_SZ*256*2);
  float* G = (float*)(ws + (size_t)B_SZ*256*2 + (size_t)B_SZ*PSD_LDA*2);
  float* S = G + (size_t)B_SZ * B_SZ;
  float2* vmean = (float2*)(S + (size_t)B_SZ * B_SZ);
  float2* wind  = vmean + B_SZ;
  float* row_loss = (float*)(wind + B_SZ);

  normalize_kernel<<<B_SZ, 256, 0, stream>>>(features, f_n);
  traj_stats_kernel<<<B_SZ, 256, 0, stream>>>((const float4*)traj, psd, vmean, wind);

  dim3 grid16(16, 16);
  gram_mfma_kernel<PSD_LDA, PSD_LDA><<<grid16, 256, 0, stream>>>(psd, G);
  gram_mfma_kernel<256, 256><<<grid16, 256, 0, stream>>>(f_n, S);

  loss_rows_kernel<<<B_SZ, 256, 0, stream>>>(S, G, labels, scales, vmean, wind, row_loss);
  reduce_mean_kernel<<<1, 256, 0, stream>>>(row_loss, (float*)d_out);
}

// Round 6
// 74.552 us; speedup vs baseline: 1.8217x; 1.8217x over previous
//
#include <hip/hip_runtime.h>
#include <hip/hip_bf16.h>
#include <hip/hip_fp16.h>

#define B_SZ 1024
#define T_LEN 8192
#define NBINS 819            // T//10
#define PSD_LDA 1664         // padded bf16 row stride (zero-padded 1638..1663)
#define PI_F 3.14159265358979323846f

typedef __attribute__((ext_vector_type(8))) short bf16x8;
typedef __attribute__((ext_vector_type(4))) float f32x4;

// ---- compile-time FFT tables ----------------------------------------------
__device__ constexpr float C32T[16] = {
  1.0f, 0.980785280f, 0.923879533f, 0.831469612f, 0.707106781f, 0.555570233f,
  0.382683432f, 0.195090322f, 0.0f, -0.195090322f, -0.382683432f, -0.555570233f,
  -0.707106781f, -0.831469612f, -0.923879533f, -0.980785280f};
__device__ constexpr float S32T[16] = {   // -sin(2*pi*k/32)
  0.0f, -0.195090322f, -0.382683432f, -0.555570233f, -0.707106781f,
  -0.831469612f, -0.923879533f, -0.980785280f, -1.0f, -0.980785280f,
  -0.923879533f, -0.831469612f, -0.707106781f, -0.555570233f, -0.382683432f,
  -0.195090322f};
__device__ constexpr int BR5[32] = {   // 5-bit bit-reverse
  0,16,8,24,4,20,12,28,2,18,10,26,6,22,14,30,
  1,17,9,25,5,21,13,29,3,19,11,27,7,23,15,31};
__device__ constexpr float E8C[8] = {  // cos(pi*c/4)  (W_8^{7c} = e^{+i pi c/4})
  1.0f, 0.707106781f, 0.0f, -0.707106781f, -1.0f, -0.707106781f, 0.0f, 0.707106781f};
__device__ constexpr float E8S[8] = {  // sin(pi*c/4)
  0.0f, 0.707106781f, 1.0f, 0.707106781f, 0.0f, -0.707106781f, -1.0f, -0.707106781f};

template<int S>
__device__ __forceinline__ void fft32_stage(float (&xr)[32], float (&xi)[32]) {
  #pragma unroll
  for (int o = 0; o < 32; o += 2 * S) {
    #pragma unroll
    for (int j = 0; j < S; ++j) {
      const int i0 = o + j, i1 = o + j + S;
      float ur = xr[i0] + xr[i1], ui = xi[i0] + xi[i1];
      float dr = xr[i0] - xr[i1], di = xi[i0] - xi[i1];
      const float c = C32T[j * (16 / S)], sn = S32T[j * (16 / S)];
      xr[i0] = ur; xi[i0] = ui;
      xr[i1] = dr * c - di * sn;
      xi[i1] = dr * sn + di * c;
    }
  }
}
__device__ __forceinline__ void fft32(float (&xr)[32], float (&xi)[32]) {
  fft32_stage<16>(xr, xi); fft32_stage<8>(xr, xi); fft32_stage<4>(xr, xi);
  fft32_stage<2>(xr, xi);  fft32_stage<1>(xr, xi);
  // X[k] sits at register index BR5[k]
}

// ---------------------------------------------------------------------------
// Kernel 1: normalize feature rows (B x 256) -> bf16
// ---------------------------------------------------------------------------
__global__ __launch_bounds__(256) void normalize_kernel(
    const float* __restrict__ f, __hip_bfloat16* __restrict__ fn) {
  int i = blockIdx.x;
  int t = threadIdx.x;
  float v = f[(size_t)i * 256 + t];
  float s = v * v;
  #pragma unroll
  for (int o = 32; o; o >>= 1) s += __shfl_down(s, o);
  __shared__ float buf[4];
  if ((t & 63) == 0) buf[t >> 6] = s;
  __syncthreads();
  float norm = sqrtf(buf[0] + buf[1] + buf[2] + buf[3]);
  norm = fmaxf(norm, 1e-12f);
  fn[(size_t)i * 256 + t] = __float2bfloat16(v / norm);
}

// ---------------------------------------------------------------------------
// Kernel 2: per-trajectory stats, 8192 = 32 x 32 x 8, fp16 LDS intermediates.
// 256 threads, 32 complex/thread; LDS 32.5 KB -> up to 4 blocks/CU.
// NO waves-per-EU hint (R5 lesson: a forced cap spilled 64+ live regs).
// n = 256a + 8b + c (tid = 8b+c); k = k0 + 32k1 + 1024k2.
//   S1: FFT32 over a -> *W_8192^{tid*k0} -> T1 (half2, swizzled)
//   S2: FFT32 over b -> *W_256^{cr*k1}   -> T2 (half2, swizzled)
//   S3: partial DFT8 over c, k2 in {0,7} -> fp32 in reused LDS
// ---------------------------------------------------------------------------
__global__ __launch_bounds__(256) void traj_stats_kernel(
    const float4* __restrict__ traj,
    __hip_bfloat16* __restrict__ psd,
    float2* __restrict__ vmean,
    float2* __restrict__ wind) {
  __shared__ __half2 z2[T_LEN];   // 32 KB
  __shared__ float rsum[2][4];
  __shared__ float phb[4];

  const int tid = threadIdx.x;
  const float4* row = traj + (size_t)blockIdx.x * T_LEN;
  const int b = tid >> 3, c = tid & 7;   // also (k0r, cr) for the read side

  if (tid == 0) {   // phase endpoints: two tiny direct loads
    float4 r0 = row[0];
    float4 r1 = row[T_LEN - 1];
    phb[0] = r0.x; phb[1] = r0.z; phb[2] = r1.x; phb[3] = r1.z;
  }

  float xr[32], xi[32];
  float sum0 = 0.f, sum1 = 0.f;
  const float wstep = 2.0f * PI_F / (float)T_LEN;

  // 8 groups of 4-deep staging (peak regs: 16 staging + accumulating data)
  #pragma unroll
  for (int g = 0; g < 8; ++g) {
    float4 rb[4];
    #pragma unroll
    for (int i = 0; i < 4; ++i) rb[i] = row[(g * 4 + i) * 256 + tid];
    #pragma unroll
    for (int i = 0; i < 4; ++i) {
      const int a = g * 4 + i;
      sum0 += rb[i].y; sum1 += rb[i].w;
      float w = 0.5f * (1.0f - __cosf(wstep * (float)(a * 256 + tid)));
      xr[a] = rb[i].y * w;
      xi[a] = rb[i].w * w;
    }
  }

  // ---- stage 1: FFT32 over a
  fft32(xr, xi);

  // twiddle W_8192^{tid*k0} fused with T1 write
  // T1 word(k0,b,c) = k0*256 + ((b + (k0&3))&31)*8 + c   (<=2-way both sides)
  {
    float s1, c1, s16, c16;
    __sincosf(-2.0f * PI_F * (float)tid / 8192.0f, &s1, &c1);
    __sincosf(-2.0f * PI_F * (float)tid / 512.0f,  &s16, &c16);
    float wr0 = 1.f, wi0 = 0.f, wr1 = c16, wi1 = s16;
    #pragma unroll
    for (int k0 = 0; k0 < 16; ++k0) {
      {
        const int r = BR5[k0];
        float tr = xr[r] * wr0 - xi[r] * wi0;
        float ti = xr[r] * wi0 + xi[r] * wr0;
        z2[k0 * 256 + (((b + (k0 & 3)) & 31) << 3) + c] = __floats2half2_rn(tr, ti);
        float nr = wr0 * c1 - wi0 * s1; wi0 = wr0 * s1 + wi0 * c1; wr0 = nr;
      }
      {
        const int k0b = k0 + 16;
        const int r = BR5[k0b];
        float tr = xr[r] * wr1 - xi[r] * wi1;
        float ti = xr[r] * wi1 + xi[r] * wr1;
        z2[k0b * 256 + (((b + (k0b & 3)) & 31) << 3) + c] = __floats2half2_rn(tr, ti);
        float nr = wr1 * c1 - wi1 * s1; wi1 = wr1 * s1 + wi1 * c1; wr1 = nr;
      }
    }
  }
  __syncthreads();

  // ---- T1 read: thread (k0r=b, cr=c) gathers over b' (static reg indices)
  #pragma unroll
  for (int bq = 0; bq < 32; ++bq) {
    __half2 v = z2[b * 256 + (((bq + (b & 3)) & 31) << 3) + c];
    xr[bq] = __low2float(v); xi[bq] = __high2float(v);
  }
  __syncthreads();   // all reads done before in-place overwrite

  // ---- stage 2: FFT32 over b
  fft32(xr, xi);

  // twiddle W_256^{cr*k1} fused with T2 write
  // T2 word(p,c) = p*8 + (c ^ ((p>>2)&7)), p = k1*32 + k0r  (<=2-way both sides)
  {
    float s1, c1, s16, c16;
    __sincosf(-2.0f * PI_F * (float)c / 256.0f, &s1, &c1);
    __sincosf(-2.0f * PI_F * (float)c / 16.0f,  &s16, &c16);
    float wr0 = 1.f, wi0 = 0.f, wr1 = c16, wi1 = s16;
    #pragma unroll
    for (int k1 = 0; k1 < 16; ++k1) {
      {
        const int r = BR5[k1];
        const int p = (k1 << 5) + b;
        float tr = xr[r] * wr0 - xi[r] * wi0;
        float ti = xr[r] * wi0 + xi[r] * wr0;
        z2[(p << 3) + (c ^ ((p >> 2) & 7))] = __floats2half2_rn(tr, ti);
        float nr = wr0 * c1 - wi0 * s1; wi0 = wr0 * s1 + wi0 * c1; wr0 = nr;
      }
      {
        const int k1b = k1 + 16;
        const int r = BR5[k1b];
        const int p = (k1b << 5) + b;
        float tr = xr[r] * wr1 - xi[r] * wi1;
        float ti = xr[r] * wi1 + xi[r] * wr1;
        z2[(p << 3) + (c ^ ((p >> 2) & 7))] = __floats2half2_rn(tr, ti);
        float nr = wr1 * c1 - wi1 * s1; wi1 = wr1 * s1 + wi1 * c1; wr1 = nr;
      }
    }
  }
  __syncthreads();

  // ---- stage 3: partial DFT8 over c; 4 p-values per thread, k2 in {0,7}
  float z0r[4], z0i[4], z7r[4], z7i[4];
  #pragma unroll
  for (int q = 0; q < 4; ++q) {
    const int p = q * 256 + tid;
    float s0r = 0.f, s0i = 0.f, s7r = 0.f, s7i = 0.f;
    #pragma unroll
    for (int c2 = 0; c2 < 8; ++c2) {
      __half2 v = z2[(p << 3) + (c2 ^ ((p >> 2) & 7))];
      float vr = __low2float(v), vi = __high2float(v);
      s0r += vr; s0i += vi;
      s7r += vr * E8C[c2] - vi * E8S[c2];
      s7i += vr * E8S[c2] + vi * E8C[c2];
    }
    z0r[q] = s0r; z0i[q] = s0i; z7r[q] = s7r; z7i[q] = s7i;
  }
  __syncthreads();   // all stage-3 reads done
  float2* zf = (float2*)z2;   // fp32 result region: 2048 float2 = 16 KB
  #pragma unroll
  for (int q = 0; q < 4; ++q) {
    const int p = q * 256 + tid;
    zf[p]        = make_float2(z0r[q], z0i[q]);   // Z[p], p in [0,1024)
    zf[1024 + p] = make_float2(z7r[q], z7i[q]);   // Z[7168+p]
  }
  __syncthreads();

  // ---- unpack packed real FFTs -> psd (bf16), zero-pad to PSD_LDA
  for (int k = tid; k < PSD_LDA / 2; k += 256) {
    if (k < NBINS) {
      float2 Zk = zf[k];
      float2 Zn = (k == 0) ? zf[0] : zf[2048 - k];   // Z[8192-k]
      float fxr = 0.5f * (Zk.x + Zn.x);
      float fxi = 0.5f * (Zk.y - Zn.y);
      float fyr = 0.5f * (Zk.y + Zn.y);
      float fyi = 0.5f * (Zn.x - Zk.x);
      psd[(size_t)blockIdx.x * PSD_LDA + 2*k]     = __float2bfloat16(fxr*fxr + fxi*fxi);
      psd[(size_t)blockIdx.x * PSD_LDA + 2*k + 1] = __float2bfloat16(fyr*fyr + fyi*fyi);
    } else {
      psd[(size_t)blockIdx.x * PSD_LDA + 2*k]     = __float2bfloat16(0.0f);
      psd[(size_t)blockIdx.x * PSD_LDA + 2*k + 1] = __float2bfloat16(0.0f);
    }
  }

  // ---- v_mean and winding
  #pragma unroll
  for (int o = 32; o; o >>= 1) {
    sum0 += __shfl_down(sum0, o);
    sum1 += __shfl_down(sum1, o);
  }
  if ((tid & 63) == 0) { rsum[0][tid >> 6] = sum0; rsum[1][tid >> 6] = sum1; }
  __syncthreads();
  if (tid == 0) {
    float s0 = rsum[0][0] + rsum[0][1] + rsum[0][2] + rsum[0][3];
    float s1v = rsum[1][0] + rsum[1][1] + rsum[1][2] + rsum[1][3];
    vmean[blockIdx.x] = make_float2(s0 / (float)T_LEN, s1v / (float)T_LEN);
    const float inv2pi = 0.15915494309189535f;
    wind[blockIdx.x] = make_float2(fabsf(rintf((phb[2] - phb[0]) * inv2pi)),
                                   fabsf(rintf((phb[3] - phb[1]) * inv2pi)));
  }
}

// ---------------------------------------------------------------------------
// Kernel 3: C = A * A^T, A (1024 x K bf16, stride LDA), MFMA 16x16x32 bf16.
// ---------------------------------------------------------------------------
template<int K, int LDA>
__global__ __launch_bounds__(256) void gram_mfma_kernel(
    const __hip_bfloat16* __restrict__ A, float* __restrict__ C) {
  __shared__ __align__(16) __hip_bfloat16 lds[2][64][64];  // 16 KB
  const int tid  = threadIdx.x;
  const int lane = tid & 63;
  const int wave = tid >> 6;
  const int wm = wave >> 1, wn = wave & 1;
  const int i0 = blockIdx.y * 64;
  const int j0 = blockIdx.x * 64;

  f32x4 acc[2][2] = {};

  for (int k0 = 0; k0 < K; k0 += 64) {
    #pragma unroll
    for (int r = 0; r < 2; ++r) {
      int e   = tid + 256 * r;
      int row = e >> 3;
      int cb  = e & 7;
      int scb = cb ^ (row & 7);
      const __hip_bfloat16* srcA = A + (size_t)(i0 + row) * LDA + k0 + scb * 8;
      const __hip_bfloat16* srcB = A + (size_t)(j0 + row) * LDA + k0 + scb * 8;
      __builtin_amdgcn_global_load_lds(
          (const __attribute__((address_space(1))) void*)srcA,
          (__attribute__((address_space(3))) void*)(&lds[0][0][0] + e * 8),
          16, 0, 0);
      __builtin_amdgcn_global_load_lds(
          (const __attribute__((address_space(1))) void*)srcB,
          (__attribute__((address_space(3))) void*)(&lds[1][0][0] + e * 8),
          16, 0, 0);
    }
    __syncthreads();

    #pragma unroll
    for (int ks = 0; ks < 2; ++ks) {
      bf16x8 afr[2], bfr[2];
      #pragma unroll
      for (int m = 0; m < 2; ++m) {
        int row = wm * 32 + m * 16 + (lane & 15);
        int cidx = ks * 4 + (lane >> 4);
        int cc  = cidx ^ (row & 7);
        afr[m] = *(const bf16x8*)(&lds[0][row][cc * 8]);
      }
      #pragma unroll
      for (int n = 0; n < 2; ++n) {
        int row = wn * 32 + n * 16 + (lane & 15);
        int cidx = ks * 4 + (lane >> 4);
        int cc  = cidx ^ (row & 7);
        bfr[n] = *(const bf16x8*)(&lds[1][row][cc * 8]);
      }
      #pragma unroll
      for (int m = 0; m < 2; ++m)
        #pragma unroll
        for (int n = 0; n < 2; ++n)
          acc[m][n] = __builtin_amdgcn_mfma_f32_16x16x32_bf16(
              afr[m], bfr[n], acc[m][n], 0, 0, 0);
    }
    __syncthreads();
  }

  #pragma unroll
  for (int m = 0; m < 2; ++m)
    #pragma unroll
    for (int n = 0; n < 2; ++n)
      #pragma unroll
      for (int r = 0; r < 4; ++r) {
        int row = i0 + wm * 32 + m * 16 + (lane >> 4) * 4 + r;
        int col = j0 + wn * 32 + n * 16 + (lane & 15);
        C[(size_t)row * B_SZ + col] = acc[m][n][r];
      }
}

// ---------------------------------------------------------------------------
// Kernel 4: per-row loss. One block per row i.
// ---------------------------------------------------------------------------
__global__ __launch_bounds__(256) void loss_rows_kernel(
    const float* __restrict__ S,
    const float* __restrict__ G,
    const float* __restrict__ labels,
    const float* __restrict__ scales,
    const float2* __restrict__ vmean,
    const float2* __restrict__ wind,
    float* __restrict__ row_loss) {
  const int i = blockIdx.x;
  const int tid = threadIdx.x;
  const float inv_scale = 1.0f / scales[0];
  const float l0 = labels[i*3+0], l1 = labels[i*3+1], l2 = labels[i*3+2];
  const float2 vmi = vmean[i];
  const float2 wi  = wind[i];
  const float n2i  = G[(size_t)i * B_SZ + i];
  const float normi = sqrtf(n2i);

  float posw = 0.f, den = 0.f;
  for (int j = tid; j < B_SZ; j += 256) {
    if (j == i) continue;
    float e = __expf(S[(size_t)i * B_SZ + j] * 10.0f);
    den += e;

    float d0 = (labels[j*3+0] - l0) * inv_scale;
    float d1 = (labels[j*3+1] - l1) * inv_scale;
    float d2v = (labels[j*3+2] - l2) * inv_scale;
    float pd = sqrtf(d0*d0 + d1*d1 + d2v*d2v);
    float pw = __expf(-pd * 10.0f);

    float2 vmj = vmean[j];
    float dvx = vmi.x - vmj.x, dvy = vmi.y - vmj.y;
    float v_sim = __expf(-sqrtf(dvx*dvx + dvy*dvy) * 2.0f);

    float n2j = G[(size_t)j * B_SZ + j];
    float g   = G[(size_t)i * B_SZ + j];
    float dd  = fmaxf(n2i + n2j - 2.0f * g, 0.0f);
    float psd_dist = sqrtf(dd);
    float norma = (i < j) ? normi : sqrtf(n2j);
    float psd_sim = __expf(-psd_dist / (norma + 1e-8f));

    float2 wj = wind[j];
    float w_sim = (wi.x == wj.x && wi.y == wj.y) ? 1.0f : 0.0f;

    float kin = 0.4f * v_sim + 0.4f * psd_sim + 0.2f * w_sim;
    posw += e * pw * kin;
  }

  #pragma unroll
  for (int o = 32; o; o >>= 1) {
    posw += __shfl_down(posw, o);
    den  += __shfl_down(den, o);
  }
  __shared__ float bp[4], bd[4];
  if ((tid & 63) == 0) { bp[tid >> 6] = posw; bd[tid >> 6] = den; }
  __syncthreads();
  if (tid == 0) {
    float P = bp[0] + bp[1] + bp[2] + bp[3];
    float D = bd[0] + bd[1] + bd[2] + bd[3];
    row_loss[i] = -logf((P + 1e-8f) / (D + 1e-8f));
  }
}

// ---------------------------------------------------------------------------
// Kernel 5: mean of row losses -> scalar
// ---------------------------------------------------------------------------
__global__ __launch_bounds__(256) void reduce_mean_kernel(
    const float* __restrict__ row_loss, float* __restrict__ out) {
  int tid = threadIdx.x;
  float s = 0.f;
  for (int i = tid; i < B_SZ; i += 256) s += row_loss[i];
  #pragma unroll
  for (int o = 32; o; o >>= 1) s += __shfl_down(s, o);
  __shared__ float buf[4];
  if ((tid & 63) == 0) buf[tid >> 6] = s;
  __syncthreads();
  if (tid == 0) out[0] = (buf[0] + buf[1] + buf[2] + buf[3]) / (float)B_SZ;
}

// ---------------------------------------------------------------------------
extern "C" void kernel_launch(void* const* d_in, const int* in_sizes, int n_in,
                              void* d_out, int out_size, void* d_ws, size_t ws_size,
                              hipStream_t stream) {
  const float* features = (const float*)d_in[0];
  const float* labels   = (const float*)d_in[1];
  const float* traj     = (const float*)d_in[2];
  const float* scales   = (const float*)d_in[3];

  char* ws = (char*)d_ws;
  __hip_bfloat16* f_n = (__hip_bfloat16*)ws;
  __hip_bfloat16* psd = (__hip_bfloat16*)(ws + (size_t)B_SZ*256*2);
  float* G = (float*)(ws + (size_t)B_SZ*256*2 + (size_t)B_SZ*PSD_LDA*2);
  float* S = G + (size_t)B_SZ * B_SZ;
  float2* vmean = (float2*)(S + (size_t)B_SZ * B_SZ);
  float2* wind  = vmean + B_SZ;
  float* row_loss = (float*)(wind + B_SZ);

  normalize_kernel<<<B_SZ, 256, 0, stream>>>(features, f_n);
  traj_stats_kernel<<<B_SZ, 256, 0, stream>>>((const float4*)traj, psd, vmean, wind);

  dim3 grid16(16, 16);
  gram_mfma_kernel<PSD_LDA, PSD_LDA><<<grid16, 256, 0, stream>>>(psd, G);
  gram_mfma_kernel<256, 256><<<grid16, 256, 0, stream>>>(f_n, S);

  loss_rows_kernel<<<B_SZ, 256, 0, stream>>>(S, G, labels, scales, vmean, wind, row_loss);
  reduce_mean_kernel<<<1, 256, 0, stream>>>(row_loss, (float*)d_out);
}

// Round 7
// 73.721 us; speedup vs baseline: 1.8422x; 1.0113x over previous
//
#include <hip/hip_runtime.h>
#include <hip/hip_bf16.h>
#include <hip/hip_fp16.h>

#define B_SZ 1024
#define T_LEN 8192
#define NBINS 819            // T//10
#define PSD_LDA 1664         // padded bf16 row stride (zero-padded 1638..1663)
#define PI_F 3.14159265358979323846f

typedef __attribute__((ext_vector_type(8))) short bf16x8;
typedef __attribute__((ext_vector_type(4))) float f32x4;

// ---- compile-time FFT tables ----------------------------------------------
__device__ constexpr float C32T[16] = {
  1.0f, 0.980785280f, 0.923879533f, 0.831469612f, 0.707106781f, 0.555570233f,
  0.382683432f, 0.195090322f, 0.0f, -0.195090322f, -0.382683432f, -0.555570233f,
  -0.707106781f, -0.831469612f, -0.923879533f, -0.980785280f};
__device__ constexpr float S32T[16] = {   // -sin(2*pi*k/32)
  0.0f, -0.195090322f, -0.382683432f, -0.555570233f, -0.707106781f,
  -0.831469612f, -0.923879533f, -0.980785280f, -1.0f, -0.980785280f,
  -0.923879533f, -0.831469612f, -0.707106781f, -0.555570233f, -0.382683432f,
  -0.195090322f};
__device__ constexpr int BR5[32] = {   // 5-bit bit-reverse
  0,16,8,24,4,20,12,28,2,18,10,26,6,22,14,30,
  1,17,9,25,5,21,13,29,3,19,11,27,7,23,15,31};
__device__ constexpr float E8C[8] = {  // cos(pi*c/4)  (W_8^{7c} = e^{+i pi c/4})
  1.0f, 0.707106781f, 0.0f, -0.707106781f, -1.0f, -0.707106781f, 0.0f, 0.707106781f};
__device__ constexpr float E8S[8] = {  // sin(pi*c/4)
  0.0f, 0.707106781f, 1.0f, 0.707106781f, 0.0f, -0.707106781f, -1.0f, -0.707106781f};

template<int S>
__device__ __forceinline__ void fft32_stage(float (&xr)[32], float (&xi)[32]) {
  #pragma unroll
  for (int o = 0; o < 32; o += 2 * S) {
    #pragma unroll
    for (int j = 0; j < S; ++j) {
      const int i0 = o + j, i1 = o + j + S;
      float ur = xr[i0] + xr[i1], ui = xi[i0] + xi[i1];
      float dr = xr[i0] - xr[i1], di = xi[i0] - xi[i1];
      const float c = C32T[j * (16 / S)], sn = S32T[j * (16 / S)];
      xr[i0] = ur; xi[i0] = ui;
      xr[i1] = dr * c - di * sn;
      xi[i1] = dr * sn + di * c;
    }
  }
}
__device__ __forceinline__ void fft32(float (&xr)[32], float (&xi)[32]) {
  fft32_stage<16>(xr, xi); fft32_stage<8>(xr, xi); fft32_stage<4>(xr, xi);
  fft32_stage<2>(xr, xi);  fft32_stage<1>(xr, xi);
  // X[k] sits at register index BR5[k]
}

// ---------------------------------------------------------------------------
// Kernel 1: normalize feature rows (B x 256) -> bf16
// ---------------------------------------------------------------------------
__global__ __launch_bounds__(256) void normalize_kernel(
    const float* __restrict__ f, __hip_bfloat16* __restrict__ fn) {
  int i = blockIdx.x;
  int t = threadIdx.x;
  float v = f[(size_t)i * 256 + t];
  float s = v * v;
  #pragma unroll
  for (int o = 32; o; o >>= 1) s += __shfl_down(s, o);
  __shared__ float buf[4];
  if ((t & 63) == 0) buf[t >> 6] = s;
  __syncthreads();
  float norm = sqrtf(buf[0] + buf[1] + buf[2] + buf[3]);
  norm = fmaxf(norm, 1e-12f);
  fn[(size_t)i * 256 + t] = __float2bfloat16(v / norm);
}

// ---------------------------------------------------------------------------
// Kernel 2: per-trajectory stats, 8192 = 32 x 32 x 8, fp16 LDS intermediates.
// 256 threads, 32 complex/thread; LDS 32.5 KB.
// Load phase: 64 scalar dword loads (y,w channels only) DIRECTLY into the
// FFT register arrays — no float4 staging (low VGPR, 64 loads in flight).
// n = 256a + 8b + c (tid = 8b+c); k = k0 + 32k1 + 1024k2.
// ---------------------------------------------------------------------------
__global__ __launch_bounds__(256) void traj_stats_kernel(
    const float* __restrict__ trajf,
    __hip_bfloat16* __restrict__ psd,
    float2* __restrict__ vmean,
    float2* __restrict__ wind) {
  __shared__ __half2 z2[T_LEN];   // 32 KB
  __shared__ float rsum[2][4];
  __shared__ float phb[4];

  const int tid = threadIdx.x;
  const float* rowf = trajf + (size_t)blockIdx.x * T_LEN * 4;
  const int b = tid >> 3, c = tid & 7;   // also (k0r, cr) for the read side

  float xr[32], xi[32];
  float sum0 = 0.f, sum1 = 0.f;
  const float wstep = 2.0f * PI_F / (float)T_LEN;

  // ---- load y,w channels straight into the data arrays (64 loads in flight)
  #pragma unroll
  for (int a = 0; a < 32; ++a) {
    const size_t base = (size_t)4 * (a * 256 + tid);
    xr[a] = rowf[base + 1];   // v-channel 0 (y)
    xi[a] = rowf[base + 3];   // v-channel 1 (w)
  }
  if (tid == 0) {   // phase endpoints
    phb[0] = rowf[0];                      // x[0]
    phb[1] = rowf[2];                      // z[0]
    phb[2] = rowf[(size_t)4 * (T_LEN - 1)];      // x[T-1]
    phb[3] = rowf[(size_t)4 * (T_LEN - 1) + 2];  // z[T-1]
  }

  // ---- sums + Hann window in-place
  #pragma unroll
  for (int a = 0; a < 32; ++a) {
    sum0 += xr[a]; sum1 += xi[a];
    float w = 0.5f * (1.0f - __cosf(wstep * (float)(a * 256 + tid)));
    xr[a] *= w;
    xi[a] *= w;
  }

  // ---- stage 1: FFT32 over a
  fft32(xr, xi);

  // twiddle W_8192^{tid*k0} fused with T1 write
  // T1 word(k0,b,c) = k0*256 + ((b + (k0&3))&31)*8 + c   (<=2-way both sides)
  {
    float s1, c1, s16, c16;
    __sincosf(-2.0f * PI_F * (float)tid / 8192.0f, &s1, &c1);
    __sincosf(-2.0f * PI_F * (float)tid / 512.0f,  &s16, &c16);
    float wr0 = 1.f, wi0 = 0.f, wr1 = c16, wi1 = s16;
    #pragma unroll
    for (int k0 = 0; k0 < 16; ++k0) {
      {
        const int r = BR5[k0];
        float tr = xr[r] * wr0 - xi[r] * wi0;
        float ti = xr[r] * wi0 + xi[r] * wr0;
        z2[k0 * 256 + (((b + (k0 & 3)) & 31) << 3) + c] = __floats2half2_rn(tr, ti);
        float nr = wr0 * c1 - wi0 * s1; wi0 = wr0 * s1 + wi0 * c1; wr0 = nr;
      }
      {
        const int k0b = k0 + 16;
        const int r = BR5[k0b];
        float tr = xr[r] * wr1 - xi[r] * wi1;
        float ti = xr[r] * wi1 + xi[r] * wr1;
        z2[k0b * 256 + (((b + (k0b & 3)) & 31) << 3) + c] = __floats2half2_rn(tr, ti);
        float nr = wr1 * c1 - wi1 * s1; wi1 = wr1 * s1 + wi1 * c1; wr1 = nr;
      }
    }
  }
  __syncthreads();

  // ---- T1 read: thread (k0r=b, cr=c) gathers over b' (static reg indices)
  #pragma unroll
  for (int bq = 0; bq < 32; ++bq) {
    __half2 v = z2[b * 256 + (((bq + (b & 3)) & 31) << 3) + c];
    xr[bq] = __low2float(v); xi[bq] = __high2float(v);
  }
  __syncthreads();   // all reads done before in-place overwrite

  // ---- stage 2: FFT32 over b
  fft32(xr, xi);

  // twiddle W_256^{cr*k1} fused with T2 write
  // T2 word(p,c) = p*8 + (c ^ ((p>>2)&7)), p = k1*32 + k0r  (<=2-way both sides)
  {
    float s1, c1, s16, c16;
    __sincosf(-2.0f * PI_F * (float)c / 256.0f, &s1, &c1);
    __sincosf(-2.0f * PI_F * (float)c / 16.0f,  &s16, &c16);
    float wr0 = 1.f, wi0 = 0.f, wr1 = c16, wi1 = s16;
    #pragma unroll
    for (int k1 = 0; k1 < 16; ++k1) {
      {
        const int r = BR5[k1];
        const int p = (k1 << 5) + b;
        float tr = xr[r] * wr0 - xi[r] * wi0;
        float ti = xr[r] * wi0 + xi[r] * wr0;
        z2[(p << 3) + (c ^ ((p >> 2) & 7))] = __floats2half2_rn(tr, ti);
        float nr = wr0 * c1 - wi0 * s1; wi0 = wr0 * s1 + wi0 * c1; wr0 = nr;
      }
      {
        const int k1b = k1 + 16;
        const int r = BR5[k1b];
        const int p = (k1b << 5) + b;
        float tr = xr[r] * wr1 - xi[r] * wi1;
        float ti = xr[r] * wi1 + xi[r] * wr1;
        z2[(p << 3) + (c ^ ((p >> 2) & 7))] = __floats2half2_rn(tr, ti);
        float nr = wr1 * c1 - wi1 * s1; wi1 = wr1 * s1 + wi1 * c1; wr1 = nr;
      }
    }
  }
  __syncthreads();

  // ---- stage 3: partial DFT8 over c; 4 p-values per thread, k2 in {0,7}
  float z0r[4], z0i[4], z7r[4], z7i[4];
  #pragma unroll
  for (int q = 0; q < 4; ++q) {
    const int p = q * 256 + tid;
    float s0r = 0.f, s0i = 0.f, s7r = 0.f, s7i = 0.f;
    #pragma unroll
    for (int c2 = 0; c2 < 8; ++c2) {
      __half2 v = z2[(p << 3) + (c2 ^ ((p >> 2) & 7))];
      float vr = __low2float(v), vi = __high2float(v);
      s0r += vr; s0i += vi;
      s7r += vr * E8C[c2] - vi * E8S[c2];
      s7i += vr * E8S[c2] + vi * E8C[c2];
    }
    z0r[q] = s0r; z0i[q] = s0i; z7r[q] = s7r; z7i[q] = s7i;
  }
  __syncthreads();   // all stage-3 reads done
  float2* zf = (float2*)z2;   // fp32 result region: 2048 float2 = 16 KB
  #pragma unroll
  for (int q = 0; q < 4; ++q) {
    const int p = q * 256 + tid;
    zf[p]        = make_float2(z0r[q], z0i[q]);   // Z[p], p in [0,1024)
    zf[1024 + p] = make_float2(z7r[q], z7i[q]);   // Z[7168+p]
  }
  __syncthreads();

  // ---- unpack packed real FFTs -> psd (bf16), zero-pad to PSD_LDA
  for (int k = tid; k < PSD_LDA / 2; k += 256) {
    if (k < NBINS) {
      float2 Zk = zf[k];
      float2 Zn = (k == 0) ? zf[0] : zf[2048 - k];   // Z[8192-k]
      float fxr = 0.5f * (Zk.x + Zn.x);
      float fxi = 0.5f * (Zk.y - Zn.y);
      float fyr = 0.5f * (Zk.y + Zn.y);
      float fyi = 0.5f * (Zn.x - Zk.x);
      psd[(size_t)blockIdx.x * PSD_LDA + 2*k]     = __float2bfloat16(fxr*fxr + fxi*fxi);
      psd[(size_t)blockIdx.x * PSD_LDA + 2*k + 1] = __float2bfloat16(fyr*fyr + fyi*fyi);
    } else {
      psd[(size_t)blockIdx.x * PSD_LDA + 2*k]     = __float2bfloat16(0.0f);
      psd[(size_t)blockIdx.x * PSD_LDA + 2*k + 1] = __float2bfloat16(0.0f);
    }
  }

  // ---- v_mean and winding
  #pragma unroll
  for (int o = 32; o; o >>= 1) {
    sum0 += __shfl_down(sum0, o);
    sum1 += __shfl_down(sum1, o);
  }
  if ((tid & 63) == 0) { rsum[0][tid >> 6] = sum0; rsum[1][tid >> 6] = sum1; }
  __syncthreads();
  if (tid == 0) {
    float s0 = rsum[0][0] + rsum[0][1] + rsum[0][2] + rsum[0][3];
    float s1v = rsum[1][0] + rsum[1][1] + rsum[1][2] + rsum[1][3];
    vmean[blockIdx.x] = make_float2(s0 / (float)T_LEN, s1v / (float)T_LEN);
    const float inv2pi = 0.15915494309189535f;
    wind[blockIdx.x] = make_float2(fabsf(rintf((phb[2] - phb[0]) * inv2pi)),
                                   fabsf(rintf((phb[3] - phb[1]) * inv2pi)));
  }
}

// ---------------------------------------------------------------------------
// Kernel 3: C = A * A^T, A (1024 x K bf16, stride LDA), MFMA 16x16x32 bf16.
// ---------------------------------------------------------------------------
template<int K, int LDA>
__global__ __launch_bounds__(256) void gram_mfma_kernel(
    const __hip_bfloat16* __restrict__ A, float* __restrict__ C) {
  __shared__ __align__(16) __hip_bfloat16 lds[2][64][64];  // 16 KB
  const int tid  = threadIdx.x;
  const int lane = tid & 63;
  const int wave = tid >> 6;
  const int wm = wave >> 1, wn = wave & 1;
  const int i0 = blockIdx.y * 64;
  const int j0 = blockIdx.x * 64;

  f32x4 acc[2][2] = {};

  for (int k0 = 0; k0 < K; k0 += 64) {
    #pragma unroll
    for (int r = 0; r < 2; ++r) {
      int e   = tid + 256 * r;
      int row = e >> 3;
      int cb  = e & 7;
      int scb = cb ^ (row & 7);
      const __hip_bfloat16* srcA = A + (size_t)(i0 + row) * LDA + k0 + scb * 8;
      const __hip_bfloat16* srcB = A + (size_t)(j0 + row) * LDA + k0 + scb * 8;
      __builtin_amdgcn_global_load_lds(
          (const __attribute__((address_space(1))) void*)srcA,
          (__attribute__((address_space(3))) void*)(&lds[0][0][0] + e * 8),
          16, 0, 0);
      __builtin_amdgcn_global_load_lds(
          (const __attribute__((address_space(1))) void*)srcB,
          (__attribute__((address_space(3))) void*)(&lds[1][0][0] + e * 8),
          16, 0, 0);
    }
    __syncthreads();

    #pragma unroll
    for (int ks = 0; ks < 2; ++ks) {
      bf16x8 afr[2], bfr[2];
      #pragma unroll
      for (int m = 0; m < 2; ++m) {
        int row = wm * 32 + m * 16 + (lane & 15);
        int cidx = ks * 4 + (lane >> 4);
        int cc  = cidx ^ (row & 7);
        afr[m] = *(const bf16x8*)(&lds[0][row][cc * 8]);
      }
      #pragma unroll
      for (int n = 0; n < 2; ++n) {
        int row = wn * 32 + n * 16 + (lane & 15);
        int cidx = ks * 4 + (lane >> 4);
        int cc  = cidx ^ (row & 7);
        bfr[n] = *(const bf16x8*)(&lds[1][row][cc * 8]);
      }
      #pragma unroll
      for (int m = 0; m < 2; ++m)
        #pragma unroll
        for (int n = 0; n < 2; ++n)
          acc[m][n] = __builtin_amdgcn_mfma_f32_16x16x32_bf16(
              afr[m], bfr[n], acc[m][n], 0, 0, 0);
    }
    __syncthreads();
  }

  #pragma unroll
  for (int m = 0; m < 2; ++m)
    #pragma unroll
    for (int n = 0; n < 2; ++n)
      #pragma unroll
      for (int r = 0; r < 4; ++r) {
        int row = i0 + wm * 32 + m * 16 + (lane >> 4) * 4 + r;
        int col = j0 + wn * 32 + n * 16 + (lane & 15);
        C[(size_t)row * B_SZ + col] = acc[m][n][r];
      }
}

// ---------------------------------------------------------------------------
// Kernel 4: per-row loss. One block per row i.
// ---------------------------------------------------------------------------
__global__ __launch_bounds__(256) void loss_rows_kernel(
    const float* __restrict__ S,
    const float* __restrict__ G,
    const float* __restrict__ labels,
    const float* __restrict__ scales,
    const float2* __restrict__ vmean,
    const float2* __restrict__ wind,
    float* __restrict__ row_loss) {
  const int i = blockIdx.x;
  const int tid = threadIdx.x;
  const float inv_scale = 1.0f / scales[0];
  const float l0 = labels[i*3+0], l1 = labels[i*3+1], l2 = labels[i*3+2];
  const float2 vmi = vmean[i];
  const float2 wi  = wind[i];
  const float n2i  = G[(size_t)i * B_SZ + i];
  const float normi = sqrtf(n2i);

  float posw = 0.f, den = 0.f;
  for (int j = tid; j < B_SZ; j += 256) {
    if (j == i) continue;
    float e = __expf(S[(size_t)i * B_SZ + j] * 10.0f);
    den += e;

    float d0 = (labels[j*3+0] - l0) * inv_scale;
    float d1 = (labels[j*3+1] - l1) * inv_scale;
    float d2v = (labels[j*3+2] - l2) * inv_scale;
    float pd = sqrtf(d0*d0 + d1*d1 + d2v*d2v);
    float pw = __expf(-pd * 10.0f);

    float2 vmj = vmean[j];
    float dvx = vmi.x - vmj.x, dvy = vmi.y - vmj.y;
    float v_sim = __expf(-sqrtf(dvx*dvx + dvy*dvy) * 2.0f);

    float n2j = G[(size_t)j * B_SZ + j];
    float g   = G[(size_t)i * B_SZ + j];
    float dd  = fmaxf(n2i + n2j - 2.0f * g, 0.0f);
    float psd_dist = sqrtf(dd);
    float norma = (i < j) ? normi : sqrtf(n2j);
    float psd_sim = __expf(-psd_dist / (norma + 1e-8f));

    float2 wj = wind[j];
    float w_sim = (wi.x == wj.x && wi.y == wj.y) ? 1.0f : 0.0f;

    float kin = 0.4f * v_sim + 0.4f * psd_sim + 0.2f * w_sim;
    posw += e * pw * kin;
  }

  #pragma unroll
  for (int o = 32; o; o >>= 1) {
    posw += __shfl_down(posw, o);
    den  += __shfl_down(den, o);
  }
  __shared__ float bp[4], bd[4];
  if ((tid & 63) == 0) { bp[tid >> 6] = posw; bd[tid >> 6] = den; }
  __syncthreads();
  if (tid == 0) {
    float P = bp[0] + bp[1] + bp[2] + bp[3];
    float D = bd[0] + bd[1] + bd[2] + bd[3];
    row_loss[i] = -logf((P + 1e-8f) / (D + 1e-8f));
  }
}

// ---------------------------------------------------------------------------
// Kernel 5: mean of row losses -> scalar
// ---------------------------------------------------------------------------
__global__ __launch_bounds__(256) void reduce_mean_kernel(
    const float* __restrict__ row_loss, float* __restrict__ out) {
  int tid = threadIdx.x;
  float s = 0.f;
  for (int i = tid; i < B_SZ; i += 256) s += row_loss[i];
  #pragma unroll
  for (int o = 32; o; o >>= 1) s += __shfl_down(s, o);
  __shared__ float buf[4];
  if ((tid & 63) == 0) buf[tid >> 6] = s;
  __syncthreads();
  if (tid == 0) out[0] = (buf[0] + buf[1] + buf[2] + buf[3]) / (float)B_SZ;
}

// ---------------------------------------------------------------------------
extern "C" void kernel_launch(void* const* d_in, const int* in_sizes, int n_in,
                              void* d_out, int out_size, void* d_ws, size_t ws_size,
                              hipStream_t stream) {
  const float* features = (const float*)d_in[0];
  const float* labels   = (const float*)d_in[1];
  const float* traj     = (const float*)d_in[2];
  const float* scales   = (const float*)d_in[3];

  char* ws = (char*)d_ws;
  __hip_bfloat16* f_n = (__hip_bfloat16*)ws;
  __hip_bfloat16* psd = (__hip_bfloat16*)(ws + (size_t)B_SZ*256*2);
  float* G = (float*)(ws + (size_t)B_SZ*256*2 + (size_t)B_SZ*PSD_LDA*2);
  float* S = G + (size_t)B_SZ * B_SZ;
  float2* vmean = (float2*)(S + (size_t)B_SZ * B_SZ);
  float2* wind  = vmean + B_SZ;
  float* row_loss = (float*)(wind + B_SZ);

  normalize_kernel<<<B_SZ, 256, 0, stream>>>(features, f_n);
  traj_stats_kernel<<<B_SZ, 256, 0, stream>>>(traj, psd, vmean, wind);

  dim3 grid16(16, 16);
  gram_mfma_kernel<PSD_LDA, PSD_LDA><<<grid16, 256, 0, stream>>>(psd, G);
  gram_mfma_kernel<256, 256><<<grid16, 256, 0, stream>>>(f_n, S);

  loss_rows_kernel<<<B_SZ, 256, 0, stream>>>(S, G, labels, scales, vmean, wind, row_loss);
  reduce_mean_kernel<<<1, 256, 0, stream>>>(row_loss, (float*)d_out);
}